// Round 1
// 204.716 us; speedup vs baseline: 1.0971x; 1.0971x over previous
//
#include <hip/hip_runtime.h>
#include <math.h>

#define B 64
#define P 16800
#define O 64
#define THRESH 0.35f
#define VALID_T 0.2f
#define HB 2048            // coarse hist bins = top 11 bits of float bits (rank >= 0)
#define HSHIFT 21
#define CCAP 4096          // per-row candidate capacity (LDS in kTail)
#define MULT 2             // priors per thread in kD1 part (registers)
#define CHB (MULT * 256)   // 512 priors per kD1 block
#define NB2 ((P + CHB - 1) / CHB)          // 33 blocks per row
#define KD1B (B * NB2)     // 2112 kD1 blocks (dispatched first = long pole)
#define KB2B (B * O / 4)   // 1024 blocks, wave-per-(b,o) kB2z jobs in the tail

__device__ __forceinline__ float smooth_l1(float x) {
    float ax = fabsf(x);
    return ax < 1.f ? 0.5f * ax * ax : ax - 0.5f;
}
// fast LSE -- used IDENTICALLY by kD1 hot path and kTail fixup (bit-identical deltas)
__device__ __forceinline__ float lse2(float c0, float c1) {
    float m = fmaxf(c0, c1);
    return m + __logf(__expf(c0 - m) + __expf(c1 - m));
}
// deferred-division IoU argmax update -- shared by hot path and fixup (bit-identical)
__device__ __forceinline__ void iou_upd(float4 t, float area_a,
                                        float px1, float py1, float px2, float py2,
                                        float area_b,
                                        float& bnum, float& bden, int& bio, int o) {
    float w = fmaxf(fminf(t.z, px2) - fmaxf(t.x, px1), 0.f);
    float h = fmaxf(fminf(t.w, py2) - fmaxf(t.y, py1), 0.f);
    float inter = w * h;
    float den = area_a + area_b - inter;
    if (inter * bden > bnum * den) { bnum = inter; bden = den; bio = o; }
}
__device__ __forceinline__ float wave_sum(float v) {
#pragma unroll
    for (int s = 32; s > 0; s >>= 1) v += __shfl_down(v, s, 64);
    return v;
}
__device__ __forceinline__ int wave_sum_i(int v) {
#pragma unroll
    for (int s = 32; s > 0; s >>= 1) v += __shfl_down(v, s, 64);
    return v;
}
__device__ __forceinline__ float wave_min(float v) {
#pragma unroll
    for (int s = 32; s > 0; s >>= 1) v = fminf(v, __shfl_xor(v, s, 64));
    return v;
}
__device__ __forceinline__ float wave_max(float v) {
#pragma unroll
    for (int s = 32; s > 0; s >>= 1) v = fmaxf(v, __shfl_xor(v, s, 64));
    return v;
}

// ---------------- kMain: kD1 blocks [0, KD1B) + kB2z wave-per-(b,o) blocks after.
// kB2z part is bit-identical to the old 64-thread kernel: each (b,o) pair is handled
// by exactly one wave with the same lane-enumeration order and shfl reduction.
__global__ void __launch_bounds__(256) kMain(
        const float* __restrict__ loc_data, const float* __restrict__ conf_data,
        const float* __restrict__ landm_data, const float* __restrict__ priors,
        const float* __restrict__ targets,
        float* __restrict__ rank, int* __restrict__ hist,
        int* __restrict__ num_pos, float* __restrict__ pos_ce,
        float* __restrict__ gsum, int* __restrict__ np1_tot,
        unsigned long long* __restrict__ bp_final) {
    if (blockIdx.x >= KD1B) {
        // ---- kB2z part: per-truth best prior via grid-pruned candidates.
        int pair = (blockIdx.x - KD1B) * 4 + (threadIdx.x >> 6);
        int lane = threadIdx.x & 63;
        int o = pair & (O - 1);
        int b = pair >> 6;                 // O == 64
        const float* tt = &targets[(b * O + o) * 15];
        float tx1 = tt[0], ty1 = tt[1], tx2 = tt[2], ty2 = tt[3];
        float area_a = (tx2 - tx1) * (ty2 - ty1);
        float4 tb = make_float4(tx1, ty1, tx2, ty2);
        float bn = 0.f, bd = 1.f;          // iou = 0 fallback
        unsigned bp = 0u;                  // p = 0 fallback (ref argmax-of-zeros)
        const int fs[6]   = {80, 80, 40, 40, 20, 20};
        const int ms[6]   = {16, 32, 64, 128, 256, 512};
        const int base[6] = {0, 6400, 12800, 14400, 16000, 16400};
#pragma unroll
        for (int c = 0; c < 6; ++c) {
            int f = fs[c];
            float inv = (float)f;                         // 640/step == f
            float h = (float)ms[c] * (0.5f / 640.f);
            int j0 = (int)floorf((tx1 - h) * inv - 0.5f) - 1; if (j0 < 0) j0 = 0;
            int j1 = (int)ceilf((tx2 + h) * inv - 0.5f) + 1;  if (j1 > f - 1) j1 = f - 1;
            int i0 = (int)floorf((ty1 - h) * inv - 0.5f) - 1; if (i0 < 0) i0 = 0;
            int i1 = (int)ceilf((ty2 + h) * inv - 0.5f) + 1;  if (i1 > f - 1) i1 = f - 1;
            if (j1 < j0 || i1 < i0) continue;
            int nj = j1 - j0 + 1;
            int n = (i1 - i0 + 1) * nj;
            float rcp_nj = 1.0f / (float)nj;
            for (int idx = lane; idx < n; idx += 64) {
                int ii = (int)((float)idx * rcp_nj);      // float-rcp div (guarded below)
                int jj = idx - ii * nj;
                if (jj < 0) { ii--; jj += nj; } else if (jj >= nj) { ii++; jj -= nj; }
                int p = base[c] + (i0 + ii) * f + (j0 + jj);
                float4 q = ((const float4*)priors)[p];
                float px1 = q.x - q.z * 0.5f, py1 = q.y - q.w * 0.5f;
                float px2 = q.x + q.z * 0.5f, py2 = q.y + q.w * 0.5f;
                float areab = (px2 - px1) * (py2 - py1);
                float w = fmaxf(fminf(tb.z, px2) - fmaxf(tb.x, px1), 0.f);
                float hh = fmaxf(fminf(tb.w, py2) - fmaxf(tb.y, py1), 0.f);
                float inter = w * hh;
                float den = area_a + areab - inter;
                float l = bn * den, r = inter * bd;
                if (r > l) { bn = inter; bd = den; bp = (unsigned)p; }
            }
        }
#pragma unroll
        for (int s = 32; s > 0; s >>= 1) {
            float no = __shfl_xor(bn, s, 64), dd = __shfl_xor(bd, s, 64);
            unsigned po = __shfl_xor(bp, s, 64);
            float l = bn * dd, r = no * bd;
            bool take = (r > l) || (r == l && po < bp);
            if (take) { bn = no; bd = dd; bp = po; }
        }
        if (lane == 0) {
            float iou = bn / bd;
            bp_final[b * O + o] = ((unsigned long long)__float_as_uint(iou) << 32)
                                | (unsigned)(0xFFFFFFFFu - bp);
        }
        return;
    }
    // ---- kD1 part (unchanged math): fused match + epilogue + coarse hist.
    int blk = blockIdx.x % NB2;
    int b = blockIdx.x / NB2;
    int p0 = blk * CHB;
    __shared__ float4 t4[O];
    __shared__ float ta[O], lab[O];
    __shared__ float lm[O][10];
    __shared__ int lhist[HB];
    __shared__ float4 wbb[4];
    __shared__ int alist[O];
    __shared__ int s_cnt;
    __shared__ float wredf[3][4];
    __shared__ int wredi[2][4];
    int tid = threadIdx.x;
    if (tid < O) {
        const float* t = &targets[(b * O + tid) * 15];
        float a0 = t[0], a1 = t[1], a2 = t[2], a3 = t[3];
        t4[tid] = make_float4(a0, a1, a2, a3);
        ta[tid] = (a2 - a0) * (a3 - a1);
        lab[tid] = t[14];
    }
    for (int i = tid; i < O * 10; i += 256)
        lm[i / 10][i % 10] = targets[b * O * 15 + (i / 10) * 15 + 4 + (i % 10)];
    for (int i = tid; i < HB; i += 256) lhist[i] = 0;
    float px1[MULT], py1[MULT], px2[MULT], py2[MULT], areab[MULT];
    float4 pr4[MULT];
    float bnum[MULT], bden[MULT]; int bi[MULT]; bool act[MULT];
    float bx1 = 1e30f, by1 = 1e30f, bx2 = -1e30f, by2 = -1e30f;
#pragma unroll
    for (int mi = 0; mi < MULT; ++mi) {
        int p = p0 + mi * 256 + tid;
        act[mi] = (p < P);
        int pc = act[mi] ? p : (P - 1);
        float4 q = ((const float4*)priors)[pc];
        pr4[mi] = q;
        px1[mi] = q.x - q.z * 0.5f; py1[mi] = q.y - q.w * 0.5f;
        px2[mi] = q.x + q.z * 0.5f; py2[mi] = q.y + q.w * 0.5f;
        areab[mi] = (px2[mi] - px1[mi]) * (py2[mi] - py1[mi]);
        bx1 = fminf(bx1, px1[mi]); by1 = fminf(by1, py1[mi]);
        bx2 = fmaxf(bx2, px2[mi]); by2 = fmaxf(by2, py2[mi]);
        bnum[mi] = 0.f; bden[mi] = 1.f; bi[mi] = 0;
    }
    bx1 = wave_min(bx1); by1 = wave_min(by1);
    bx2 = wave_max(bx2); by2 = wave_max(by2);
    int wid = tid >> 6, lid = tid & 63;
    if (lid == 0) wbb[wid] = make_float4(bx1, by1, bx2, by2);
    __syncthreads();
    if (tid < 64) {
        float ux1 = fminf(fminf(wbb[0].x, wbb[1].x), fminf(wbb[2].x, wbb[3].x));
        float uy1 = fminf(fminf(wbb[0].y, wbb[1].y), fminf(wbb[2].y, wbb[3].y));
        float ux2 = fmaxf(fmaxf(wbb[0].z, wbb[1].z), fmaxf(wbb[2].z, wbb[3].z));
        float uy2 = fmaxf(fmaxf(wbb[0].w, wbb[1].w), fmaxf(wbb[2].w, wbb[3].w));
        float4 t = t4[tid];
        bool pass = (fminf(t.z, ux2) - fmaxf(t.x, ux1) > 0.f) &&
                    (fminf(t.w, uy2) - fmaxf(t.y, uy1) > 0.f);
        unsigned long long mask = __ballot(pass);
        if (tid == 0) s_cnt = __popcll(mask);
        if (pass) {
            int pos = __popcll(mask & ((1ull << tid) - 1ull));
            alist[pos] = tid;          // ballot-compaction preserves increasing o
        }
    }
    __syncthreads();
    int cnt = s_cnt;
    for (int li = 0; li < cnt; ++li) {
        int o = alist[li];
        float4 t = t4[o];
        float w0 = fminf(t.z, bx2) - fmaxf(t.x, bx1);
        float h0 = fminf(t.w, by2) - fmaxf(t.y, by1);
        if (w0 <= 0.f || h0 <= 0.f) continue;   // wave-uniform refinement (iou==0 skip)
        float area_a = ta[o];
#pragma unroll
        for (int mi = 0; mi < MULT; ++mi)
            iou_upd(t, area_a, px1[mi], py1[mi], px2[mi], py2[mi], areab[mi],
                    bnum[mi], bden[mi], bi[mi], o);
    }
    float ll = 0.f, llm = 0.f, cep = 0.f;
    int cp = 0, cp1 = 0;
#pragma unroll
    for (int mi = 0; mi < MULT; ++mi) {
        if (!act[mi]) continue;
        int p = p0 + mi * 256 + tid;
        float best = bnum[mi] / bden[mi];
        int conf = (best >= THRESH) ? (int)lab[bi[mi]] : 0;   // label +-1.0 exact
        float2 c01 = ((const float2*)conf_data)[b * P + p];
        float c0 = c01.x, c1 = c01.y;
        float lse = lse2(c0, c1);
        bool pos = conf != 0;
        float ce = lse - (pos ? c1 : c0);
        float rv = pos ? 0.f : ce;
        rank[(size_t)b * P + p] = rv;
        atomicAdd(&lhist[__float_as_uint(rv) >> HSHIFT], 1);
        if (pos) {
            cp++; cep += ce;
            int ti = bi[mi];
            float cx = pr4[mi].x, cy = pr4[mi].y, sw = pr4[mi].z, sh = pr4[mi].w;
            float4 t = t4[ti];
            float gx = ((t.x + t.z) * 0.5f - cx) / (0.1f * sw);
            float gy = ((t.y + t.w) * 0.5f - cy) / (0.1f * sh);
            float gw = logf((t.z - t.x) / sw) / 0.2f;
            float gh = logf((t.w - t.y) / sh) / 0.2f;
            const float* ld = &loc_data[(size_t)(b * P + p) * 4];
            ll += smooth_l1(ld[0] - gx) + smooth_l1(ld[1] - gy) +
                  smooth_l1(ld[2] - gw) + smooth_l1(ld[3] - gh);
            if (conf > 0) {
                cp1++;
                const float* lmd = &landm_data[(size_t)(b * P + p) * 10];
                for (int k5 = 0; k5 < 5; ++k5) {
                    float lx = (lm[ti][k5 * 2 + 0] - cx) / (0.1f * sw);
                    float ly = (lm[ti][k5 * 2 + 1] - cy) / (0.1f * sh);
                    llm += smooth_l1(lmd[k5 * 2 + 0] - lx) + smooth_l1(lmd[k5 * 2 + 1] - ly);
                }
            }
        }
    }
    float s_ll = wave_sum(ll), s_llm = wave_sum(llm), s_cep = wave_sum(cep);
    int s_cp = wave_sum_i(cp), s_cp1 = wave_sum_i(cp1);
    if (lid == 0) {
        wredf[0][wid] = s_ll; wredf[1][wid] = s_llm; wredf[2][wid] = s_cep;
        wredi[0][wid] = s_cp; wredi[1][wid] = s_cp1;
    }
    __syncthreads();
    if (tid == 0) {
        float ll_t = wredf[0][0] + wredf[0][1] + wredf[0][2] + wredf[0][3];
        float llm_t = wredf[1][0] + wredf[1][1] + wredf[1][2] + wredf[1][3];
        float cep_t = wredf[2][0] + wredf[2][1] + wredf[2][2] + wredf[2][3];
        int cp_t = wredi[0][0] + wredi[0][1] + wredi[0][2] + wredi[0][3];
        int cp1_t = wredi[1][0] + wredi[1][1] + wredi[1][2] + wredi[1][3];
        if (ll_t != 0.f)  atomicAdd(&gsum[0], ll_t);
        if (llm_t != 0.f) atomicAdd(&gsum[1], llm_t);
        if (cep_t != 0.f) atomicAdd(&pos_ce[b], cep_t);
        if (cp_t)  atomicAdd(&num_pos[b], cp_t);
        if (cp1_t) atomicAdd(np1_tot, cp1_t);
    }
    int* gh = hist + (size_t)b * HB;
#pragma unroll
    for (int i = tid; i < HB; i += 256) {
        int c = lhist[i];
        if (c) atomicAdd(&gh[i], c);
    }
}

// ---------------- kTail: fused kC2 (fixup+findbin) + kE1 (scan) + kE2 (resolve).
// One 1024-thread block per row; candidates stay in LDS (no global round-trip).
__global__ void __launch_bounds__(1024) kTail(
        const float* __restrict__ priors, const float* __restrict__ targets,
        const float* __restrict__ loc_data, const float* __restrict__ conf_data,
        const float* __restrict__ landm_data,
        const unsigned long long* __restrict__ bp_final,
        float* __restrict__ rank, const int* __restrict__ hist,
        const int* __restrict__ num_pos, const float* __restrict__ pos_ce,
        float* __restrict__ gsum, int* __restrict__ np1_tot, int* __restrict__ np_tot,
        float* __restrict__ lossc_tot, int* __restrict__ done,
        float* __restrict__ out) {
    int b = blockIdx.x;
    int tid = threadIdx.x;
    __shared__ float4 t4[O];
    __shared__ float ta[O], lab[O];
    __shared__ int sp[O];
    __shared__ int lh[HB];
    __shared__ int chunkSum[256];
    __shared__ int s_np, s_bin0, s_kk0, s_cnt;
    __shared__ unsigned lcand[CCAP];
    __shared__ float wredf[16];
    __shared__ int wredi[16];
    __shared__ float s_sumgt;
    __shared__ int hist2[256];
    __shared__ int s_bin, s_kk;

    for (int i = tid; i < HB; i += 1024) lh[i] = hist[(size_t)b * HB + i];
    int p = 0, v = 0;
    if (tid < O) {
        const float* tt = &targets[(b * O + tid) * 15];
        float4 tj = make_float4(tt[0], tt[1], tt[2], tt[3]);
        t4[tid] = tj;
        ta[tid] = (tj.z - tj.x) * (tj.w - tj.y);
        lab[tid] = tt[14];
        unsigned long long kpk = bp_final[b * O + tid];
        p = (int)(0xFFFFFFFFu - (unsigned)(kpk & 0xFFFFFFFFu));
        float iou = __uint_as_float((unsigned)(kpk >> 32));
        v = (iou >= VALID_T) ? 1 : 0;
        sp[tid] = p;
    }
    if (tid == 0) s_cnt = 0;
    __syncthreads();
    // ---- fixup (bit-identical to old kC2)
    int dnp = 0, dn1 = 0;
    float dll = 0.f, dllm = 0.f, dce = 0.f;
    if (tid < O) {
        int j = tid;
        bool winner = true;                // last j with this p wins (numpy scatter)
        for (int jj = j + 1; jj < O; ++jj)
            if (sp[jj] == p) { winner = false; break; }
        if (winner) {
            float4 q = ((const float4*)priors)[p];
            float px1 = q.x - q.z * 0.5f, py1 = q.y - q.w * 0.5f;
            float px2 = q.x + q.z * 0.5f, py2 = q.y + q.w * 0.5f;
            float areab = (px2 - px1) * (py2 - py1);
            float bnum = 0.f, bden = 1.f; int bi = 0;
            for (int o = 0; o < O; ++o)     // ascending o: bit-identical to hot path
                iou_upd(t4[o], ta[o], px1, py1, px2, py2, areab, bnum, bden, bi, o);
            float best = bnum / bden;
            float ov_new = v ? 2.0f : best;
            int conf_old = (best >= THRESH) ? (int)lab[bi] : 0;
            int conf_new = (ov_new >= THRESH) ? (int)lab[j] : 0;
            float2 c01 = ((const float2*)conf_data)[b * P + p];
            float c0 = c01.x, c1 = c01.y;
            float lse = lse2(c0, c1);
            bool po = conf_old != 0, pn = conf_new != 0;
            float ceo = lse - (po ? c1 : c0), cen = lse - (pn ? c1 : c0);
            float rvo = po ? 0.f : ceo, rvn = pn ? 0.f : cen;
            if (__float_as_uint(rvo) != __float_as_uint(rvn)) {
                rank[(size_t)b * P + p] = rvn;
                int bo = __float_as_uint(rvo) >> HSHIFT, bn = __float_as_uint(rvn) >> HSHIFT;
                if (bo != bn) { atomicAdd(&lh[bn], 1); atomicAdd(&lh[bo], -1); }
            }
            const float* ld = &loc_data[(size_t)(b * P + p) * 4];
            auto enc_ll = [&](int ti) -> float {    // same float ops as kD1 epilogue
                float4 t = t4[ti];
                float gx = ((t.x + t.z) * 0.5f - q.x) / (0.1f * q.z);
                float gy = ((t.y + t.w) * 0.5f - q.y) / (0.1f * q.w);
                float gw = logf((t.z - t.x) / q.z) / 0.2f;
                float gh = logf((t.w - t.y) / q.w) / 0.2f;
                return smooth_l1(ld[0] - gx) + smooth_l1(ld[1] - gy) +
                       smooth_l1(ld[2] - gw) + smooth_l1(ld[3] - gh);
            };
            if (po) dll -= enc_ll(bi);
            if (pn) dll += enc_ll(j);
            dce = (pn ? cen : 0.f) - (po ? ceo : 0.f);
            dnp = (int)pn - (int)po;
            const float* lmd = &landm_data[(size_t)(b * P + p) * 10];
            auto enc_lm = [&](int ti) -> float {
                const float* lmt = &targets[(b * O + ti) * 15 + 4];
                float sum = 0.f;
                for (int k5 = 0; k5 < 5; ++k5) {
                    float lx = (lmt[k5 * 2 + 0] - q.x) / (0.1f * q.z);
                    float ly = (lmt[k5 * 2 + 1] - q.y) / (0.1f * q.w);
                    sum += smooth_l1(lmd[k5 * 2 + 0] - lx) + smooth_l1(lmd[k5 * 2 + 1] - ly);
                }
                return sum;
            };
            if (conf_old > 0) dllm -= enc_lm(bi);
            if (conf_new > 0) dllm += enc_lm(j);
            dn1 = (int)(conf_new > 0) - (int)(conf_old > 0);
        }
    }
    float pce_reg = 0.f;
    if (tid < 64) {                        // wave 0 reduces the deltas
        float r_ll = wave_sum(dll), r_lm = wave_sum(dllm), r_ce = wave_sum(dce);
        int r_np = wave_sum_i(dnp), r_n1 = wave_sum_i(dn1);
        if (tid == 0) {
            if (r_ll != 0.f) atomicAdd(&gsum[0], r_ll);
            if (r_lm != 0.f) atomicAdd(&gsum[1], r_lm);
            pce_reg = pos_ce[b] + r_ce;    // row-private, kept in tid0's register
            int np = num_pos[b] + r_np;
            s_np = np;
            atomicAdd(np_tot, np);
            if (r_n1) atomicAdd(np1_tot, r_n1);
        }
    }
    __threadfence_block();                 // rank fixup writes visible block-wide
    __syncthreads();
    // ---- findbin (hist final in lh)
    int k = s_np * 7;
    if (k > P - 1) k = P - 1;
    if (tid < 256) {
        int cs = 0;
#pragma unroll
        for (int i = 0; i < HB / 256; ++i) cs += lh[tid * (HB / 256) + i];
        chunkSum[tid] = cs;
    }
    __syncthreads();
    if (tid == 0) {
        if (k <= 0) { s_bin0 = -1; s_kk0 = 0; }
        else {
            int cum = 0, bin = 0, kk = k;
            for (int c = 255; c >= 0; --c) {
                if (cum + chunkSum[c] >= k) {
                    for (int i = HB / 256 - 1; i >= 0; --i) {
                        int hv = lh[c * (HB / 256) + i];
                        if (cum + hv >= k) { bin = c * (HB / 256) + i; kk = k - cum; goto found; }
                        cum += hv;
                    }
                }
                cum += chunkSum[c];
            }
        found:
            s_bin0 = bin; s_kk0 = kk;
        }
    }
    __syncthreads();
    int bin = s_bin0;
    float topk_b = 0.f;
    if (bin >= 0) {                        // block-uniform branch: barriers safe
        // ---- row scan (old kE1): sum above bin + gather in-bin candidates to LDS
        unsigned lo_bound = ((unsigned)(bin + 1)) << HSHIFT;
        const float* r = rank + (size_t)b * P;
        float sumgt = 0.f;
        for (int pp = tid; pp < P; pp += 1024) {
            float val = r[pp];
            unsigned u = __float_as_uint(val);
            if (u >= lo_bound) sumgt += val;
            else if ((u >> HSHIFT) == (unsigned)bin) {
                int idx = atomicAdd(&s_cnt, 1);
                if (idx < CCAP) lcand[idx] = u;
            }
        }
        float sg = wave_sum(sumgt);
        if ((tid & 63) == 0) wredf[tid >> 6] = sg;
        __syncthreads();
        if (tid == 0) {
            float t = 0.f;
            for (int i = 0; i < 16; ++i) t += wredf[i];
            s_sumgt = t;
        }
        // ---- resolve (old kE2): 3-pass radix refine over LDS candidates
        int m = s_cnt;
        int kk0 = s_kk0;
        bool useG = (m > CCAP);            // pathological overflow: rescan row
        unsigned pref = ((unsigned)bin) << HSHIFT;
        unsigned resolved = 0xFFFFFFFFu << HSHIFT;
        int kk = kk0;
        const int shifts[3] = {13, 5, 0};
        const int nbins[3] = {256, 256, 32};
        for (int pass = 0; pass < 3; ++pass) {
            int sh = shifts[pass], nb = nbins[pass];
            for (int i = tid; i < nb; i += 1024) hist2[i] = 0;
            __syncthreads();
            if (!useG) {
                for (int i = tid; i < m; i += 1024) {
                    unsigned u = lcand[i];
                    if ((u & resolved) == pref) atomicAdd(&hist2[(u >> sh) & (nb - 1)], 1);
                }
            } else {
                for (int pp = tid; pp < P; pp += 1024) {
                    unsigned u = __float_as_uint(r[pp]);
                    if ((u & resolved) == pref) atomicAdd(&hist2[(u >> sh) & (nb - 1)], 1);
                }
            }
            __syncthreads();
            if (tid == 0) {
                int cum = 0, d = 0, kn = kk;
                for (int i = nb - 1; i >= 0; --i) {
                    if (cum + hist2[i] >= kk) { d = i; kn = kk - cum; break; }
                    cum += hist2[i];
                }
                s_bin = d; s_kk = kn;
            }
            __syncthreads();
            pref |= ((unsigned)s_bin) << sh;
            resolved |= (unsigned)(nb - 1) << sh;
            kk = s_kk;
            __syncthreads();
        }
        float tv = __uint_as_float(pref);  // exact k-th largest value
        float sumS = 0.f; int cntS = 0;
        if (!useG) {
            for (int i = tid; i < m; i += 1024) {
                float val = __uint_as_float(lcand[i]);
                if (val > tv) { sumS += val; cntS++; }
            }
        } else {
            for (int pp = tid; pp < P; pp += 1024) {
                unsigned u = __float_as_uint(r[pp]);
                if ((u >> HSHIFT) == (unsigned)bin) {
                    float val = __uint_as_float(u);
                    if (val > tv) { sumS += val; cntS++; }
                }
            }
        }
        float s2 = wave_sum(sumS); int c2 = wave_sum_i(cntS);
        if ((tid & 63) == 0) { wredf[tid >> 6] = s2; wredi[tid >> 6] = c2; }
        __syncthreads();
        if (tid == 0) {
            float st = 0.f; int ct = 0;
            for (int i = 0; i < 16; ++i) { st += wredf[i]; ct += wredi[i]; }
            topk_b = s_sumgt + st + (float)(kk0 - ct) * tv;
        }
    }
    if (tid == 0) {
        atomicAdd(lossc_tot, pce_reg + topk_b);
        __threadfence();
        int old = atomicAdd(done, 1);
        if (old == B - 1) {                // last block finalizes (atomic reads: L2-fresh)
            float g0 = atomicAdd(&gsum[0], 0.f);
            float g1 = atomicAdd(&gsum[1], 0.f);
            float lc = atomicAdd(lossc_tot, 0.f);
            int np = atomicAdd(np_tot, 0);
            int n1 = atomicAdd(np1_tot, 0);
            float N = fmaxf((float)np, 1.f);
            float N1 = fmaxf((float)n1, 1.f);
            out[0] = g0 / N;
            out[1] = lc / N;
            out[2] = g1 / N1;
        }
    }
}

extern "C" void kernel_launch(void* const* d_in, const int* in_sizes, int n_in,
                              void* d_out, int out_size, void* d_ws, size_t ws_size,
                              hipStream_t stream) {
    const float* loc_data   = (const float*)d_in[0];
    const float* conf_data  = (const float*)d_in[1];
    const float* landm_data = (const float*)d_in[2];
    const float* priors     = (const float*)d_in[3];
    const float* targets    = (const float*)d_in[4];
    float* out = (float*)d_out;

    char* ws = (char*)d_ws;
    size_t off = 0;
    auto alloc = [&](size_t bytes) -> void* {
        void* pp = ws + off;
        off += (bytes + 255) & ~(size_t)255;
        return pp;
    };
    float* rank     = (float*)alloc((size_t)B * P * 4);
    unsigned long long* bp_final = (unsigned long long*)alloc((size_t)B * O * 8);
    // zero region: hist (B*HB ints) + accumulators, contiguous (one memset)
    size_t hist_bytes = (size_t)B * HB * 4;
    char* zbase = (char*)alloc(hist_bytes);
    int* hist = (int*)zbase;
    size_t acc_bytes = (size_t)(2 * B * 4 + 64);
    char* acc = (char*)alloc(acc_bytes);
    int*   num_pos      = (int*)acc;
    float* pos_ce       = (float*)(acc + B * 4);
    float* gsum         = (float*)(acc + 2 * B * 4);          // 2 floats
    int*   np1_tot      = (int*)(acc + 2 * B * 4 + 8);
    int*   np_tot       = (int*)(acc + 2 * B * 4 + 12);
    float* lossc_tot    = (float*)(acc + 2 * B * 4 + 16);
    int*   done         = (int*)(acc + 2 * B * 4 + 20);
    size_t zlen = (size_t)((acc + acc_bytes) - zbase);

    hipMemsetAsync(zbase, 0, zlen, stream);
    kMain<<<dim3(KD1B + KB2B), dim3(256), 0, stream>>>(loc_data, conf_data, landm_data,
                                                       priors, targets, rank, hist,
                                                       num_pos, pos_ce, gsum, np1_tot,
                                                       bp_final);
    kTail<<<dim3(B), dim3(1024), 0, stream>>>(priors, targets, loc_data, conf_data,
                                              landm_data, bp_final, rank, hist,
                                              num_pos, pos_ce, gsum, np1_tot, np_tot,
                                              lossc_tot, done, out);
}

// Round 2
// 165.154 us; speedup vs baseline: 1.3599x; 1.2395x over previous
//
#include <hip/hip_runtime.h>
#include <math.h>

#define B 64
#define P 16800
#define O 64
#define THRESH 0.35f
#define VALID_T 0.2f
#define HB 2048            // coarse hist bins = top 11 bits of float bits (rank >= 0)
#define HSHIFT 21
#define MULT 2             // priors per thread in kD1 part (registers)
#define CHB (MULT * 256)   // 512 priors per kD1 block
#define NB2 ((P + CHB - 1) / CHB)          // 33 blocks per row
#define KD1B (B * NB2)     // 2112 kD1 blocks (dispatched first = long pole)
#define KB2B (B * O / 4)   // 1024 blocks, wave-per-(b,o) kB2z jobs in the tail

__device__ __forceinline__ float smooth_l1(float x) {
    float ax = fabsf(x);
    return ax < 1.f ? 0.5f * ax * ax : ax - 0.5f;
}
// fast LSE -- used IDENTICALLY by kD1 hot path and kTail fixup (bit-identical deltas)
__device__ __forceinline__ float lse2(float c0, float c1) {
    float m = fmaxf(c0, c1);
    return m + __logf(__expf(c0 - m) + __expf(c1 - m));
}
// deferred-division IoU argmax update -- shared by hot path and fixup (bit-identical)
__device__ __forceinline__ void iou_upd(float4 t, float area_a,
                                        float px1, float py1, float px2, float py2,
                                        float area_b,
                                        float& bnum, float& bden, int& bio, int o) {
    float w = fmaxf(fminf(t.z, px2) - fmaxf(t.x, px1), 0.f);
    float h = fmaxf(fminf(t.w, py2) - fmaxf(t.y, py1), 0.f);
    float inter = w * h;
    float den = area_a + area_b - inter;
    if (inter * bden > bnum * den) { bnum = inter; bden = den; bio = o; }
}
__device__ __forceinline__ float wave_sum(float v) {
#pragma unroll
    for (int s = 32; s > 0; s >>= 1) v += __shfl_down(v, s, 64);
    return v;
}
__device__ __forceinline__ int wave_sum_i(int v) {
#pragma unroll
    for (int s = 32; s > 0; s >>= 1) v += __shfl_down(v, s, 64);
    return v;
}
__device__ __forceinline__ float wave_min(float v) {
#pragma unroll
    for (int s = 32; s > 0; s >>= 1) v = fminf(v, __shfl_xor(v, s, 64));
    return v;
}
__device__ __forceinline__ float wave_max(float v) {
#pragma unroll
    for (int s = 32; s > 0; s >>= 1) v = fmaxf(v, __shfl_xor(v, s, 64));
    return v;
}
// inclusive suffix-sum within a 64-lane wave (lane i -> sum of lanes i..63)
__device__ __forceinline__ int wave_sufscan(int v, int lane) {
#pragma unroll
    for (int s = 1; s < 64; s <<= 1) {
        int o = __shfl_down(v, s, 64);
        if (lane + s < 64) v += o;
    }
    return v;
}

// ---------------- kMain: kD1 blocks [0, KD1B) + kB2z wave-per-(b,o) blocks after.
__global__ void __launch_bounds__(256) kMain(
        const float* __restrict__ loc_data, const float* __restrict__ conf_data,
        const float* __restrict__ landm_data, const float* __restrict__ priors,
        const float* __restrict__ targets,
        float* __restrict__ rank, int* __restrict__ hist,
        int* __restrict__ num_pos, float* __restrict__ pos_ce,
        float* __restrict__ gsum, int* __restrict__ np1_tot,
        unsigned long long* __restrict__ bp_final) {
    if (blockIdx.x >= KD1B) {
        // ---- kB2z part: per-truth best prior via grid-pruned candidates.
        int pair = (blockIdx.x - KD1B) * 4 + (threadIdx.x >> 6);
        int lane = threadIdx.x & 63;
        int o = pair & (O - 1);
        int b = pair >> 6;                 // O == 64
        const float* tt = &targets[(b * O + o) * 15];
        float tx1 = tt[0], ty1 = tt[1], tx2 = tt[2], ty2 = tt[3];
        float area_a = (tx2 - tx1) * (ty2 - ty1);
        float4 tb = make_float4(tx1, ty1, tx2, ty2);
        float bn = 0.f, bd = 1.f;          // iou = 0 fallback
        unsigned bp = 0u;                  // p = 0 fallback (ref argmax-of-zeros)
        const int fs[6]   = {80, 80, 40, 40, 20, 20};
        const int ms[6]   = {16, 32, 64, 128, 256, 512};
        const int base[6] = {0, 6400, 12800, 14400, 16000, 16400};
#pragma unroll
        for (int c = 0; c < 6; ++c) {
            int f = fs[c];
            float inv = (float)f;                         // 640/step == f
            float h = (float)ms[c] * (0.5f / 640.f);
            int j0 = (int)floorf((tx1 - h) * inv - 0.5f) - 1; if (j0 < 0) j0 = 0;
            int j1 = (int)ceilf((tx2 + h) * inv - 0.5f) + 1;  if (j1 > f - 1) j1 = f - 1;
            int i0 = (int)floorf((ty1 - h) * inv - 0.5f) - 1; if (i0 < 0) i0 = 0;
            int i1 = (int)ceilf((ty2 + h) * inv - 0.5f) + 1;  if (i1 > f - 1) i1 = f - 1;
            if (j1 < j0 || i1 < i0) continue;
            int nj = j1 - j0 + 1;
            int n = (i1 - i0 + 1) * nj;
            float rcp_nj = 1.0f / (float)nj;
            for (int idx = lane; idx < n; idx += 64) {
                int ii = (int)((float)idx * rcp_nj);      // float-rcp div (guarded below)
                int jj = idx - ii * nj;
                if (jj < 0) { ii--; jj += nj; } else if (jj >= nj) { ii++; jj -= nj; }
                int p = base[c] + (i0 + ii) * f + (j0 + jj);
                float4 q = ((const float4*)priors)[p];
                float px1 = q.x - q.z * 0.5f, py1 = q.y - q.w * 0.5f;
                float px2 = q.x + q.z * 0.5f, py2 = q.y + q.w * 0.5f;
                float areab = (px2 - px1) * (py2 - py1);
                float w = fmaxf(fminf(tb.z, px2) - fmaxf(tb.x, px1), 0.f);
                float hh = fmaxf(fminf(tb.w, py2) - fmaxf(tb.y, py1), 0.f);
                float inter = w * hh;
                float den = area_a + areab - inter;
                float l = bn * den, r = inter * bd;
                if (r > l) { bn = inter; bd = den; bp = (unsigned)p; }
            }
        }
#pragma unroll
        for (int s = 32; s > 0; s >>= 1) {
            float no = __shfl_xor(bn, s, 64), dd = __shfl_xor(bd, s, 64);
            unsigned po = __shfl_xor(bp, s, 64);
            float l = bn * dd, r = no * bd;
            bool take = (r > l) || (r == l && po < bp);
            if (take) { bn = no; bd = dd; bp = po; }
        }
        if (lane == 0) {
            float iou = bn / bd;
            bp_final[b * O + o] = ((unsigned long long)__float_as_uint(iou) << 32)
                                | (unsigned)(0xFFFFFFFFu - bp);
        }
        return;
    }
    // ---- kD1 part (unchanged math): fused match + epilogue + coarse hist.
    int blk = blockIdx.x % NB2;
    int b = blockIdx.x / NB2;
    int p0 = blk * CHB;
    __shared__ float4 t4[O];
    __shared__ float ta[O], lab[O];
    __shared__ float lm[O][10];
    __shared__ int lhist[HB];
    __shared__ float4 wbb[4];
    __shared__ int alist[O];
    __shared__ int s_cnt;
    __shared__ float wredf[3][4];
    __shared__ int wredi[2][4];
    int tid = threadIdx.x;
    if (tid < O) {
        const float* t = &targets[(b * O + tid) * 15];
        float a0 = t[0], a1 = t[1], a2 = t[2], a3 = t[3];
        t4[tid] = make_float4(a0, a1, a2, a3);
        ta[tid] = (a2 - a0) * (a3 - a1);
        lab[tid] = t[14];
    }
    for (int i = tid; i < O * 10; i += 256)
        lm[i / 10][i % 10] = targets[b * O * 15 + (i / 10) * 15 + 4 + (i % 10)];
    for (int i = tid; i < HB; i += 256) lhist[i] = 0;
    float px1[MULT], py1[MULT], px2[MULT], py2[MULT], areab[MULT];
    float4 pr4[MULT];
    float bnum[MULT], bden[MULT]; int bi[MULT]; bool act[MULT];
    float bx1 = 1e30f, by1 = 1e30f, bx2 = -1e30f, by2 = -1e30f;
#pragma unroll
    for (int mi = 0; mi < MULT; ++mi) {
        int p = p0 + mi * 256 + tid;
        act[mi] = (p < P);
        int pc = act[mi] ? p : (P - 1);
        float4 q = ((const float4*)priors)[pc];
        pr4[mi] = q;
        px1[mi] = q.x - q.z * 0.5f; py1[mi] = q.y - q.w * 0.5f;
        px2[mi] = q.x + q.z * 0.5f; py2[mi] = q.y + q.w * 0.5f;
        areab[mi] = (px2[mi] - px1[mi]) * (py2[mi] - py1[mi]);
        bx1 = fminf(bx1, px1[mi]); by1 = fminf(by1, py1[mi]);
        bx2 = fmaxf(bx2, px2[mi]); by2 = fmaxf(by2, py2[mi]);
        bnum[mi] = 0.f; bden[mi] = 1.f; bi[mi] = 0;
    }
    bx1 = wave_min(bx1); by1 = wave_min(by1);
    bx2 = wave_max(bx2); by2 = wave_max(by2);
    int wid = tid >> 6, lid = tid & 63;
    if (lid == 0) wbb[wid] = make_float4(bx1, by1, bx2, by2);
    __syncthreads();
    if (tid < 64) {
        float ux1 = fminf(fminf(wbb[0].x, wbb[1].x), fminf(wbb[2].x, wbb[3].x));
        float uy1 = fminf(fminf(wbb[0].y, wbb[1].y), fminf(wbb[2].y, wbb[3].y));
        float ux2 = fmaxf(fmaxf(wbb[0].z, wbb[1].z), fmaxf(wbb[2].z, wbb[3].z));
        float uy2 = fmaxf(fmaxf(wbb[0].w, wbb[1].w), fmaxf(wbb[2].w, wbb[3].w));
        float4 t = t4[tid];
        bool pass = (fminf(t.z, ux2) - fmaxf(t.x, ux1) > 0.f) &&
                    (fminf(t.w, uy2) - fmaxf(t.y, uy1) > 0.f);
        unsigned long long mask = __ballot(pass);
        if (tid == 0) s_cnt = __popcll(mask);
        if (pass) {
            int pos = __popcll(mask & ((1ull << tid) - 1ull));
            alist[pos] = tid;          // ballot-compaction preserves increasing o
        }
    }
    __syncthreads();
    int cnt = s_cnt;
    for (int li = 0; li < cnt; ++li) {
        int o = alist[li];
        float4 t = t4[o];
        float w0 = fminf(t.z, bx2) - fmaxf(t.x, bx1);
        float h0 = fminf(t.w, by2) - fmaxf(t.y, by1);
        if (w0 <= 0.f || h0 <= 0.f) continue;   // wave-uniform refinement (iou==0 skip)
        float area_a = ta[o];
#pragma unroll
        for (int mi = 0; mi < MULT; ++mi)
            iou_upd(t, area_a, px1[mi], py1[mi], px2[mi], py2[mi], areab[mi],
                    bnum[mi], bden[mi], bi[mi], o);
    }
    float ll = 0.f, llm = 0.f, cep = 0.f;
    int cp = 0, cp1 = 0;
#pragma unroll
    for (int mi = 0; mi < MULT; ++mi) {
        if (!act[mi]) continue;
        int p = p0 + mi * 256 + tid;
        float best = bnum[mi] / bden[mi];
        int conf = (best >= THRESH) ? (int)lab[bi[mi]] : 0;   // label +-1.0 exact
        float2 c01 = ((const float2*)conf_data)[b * P + p];
        float c0 = c01.x, c1 = c01.y;
        float lse = lse2(c0, c1);
        bool pos = conf != 0;
        float ce = lse - (pos ? c1 : c0);
        float rv = pos ? 0.f : ce;
        rank[(size_t)b * P + p] = rv;
        atomicAdd(&lhist[__float_as_uint(rv) >> HSHIFT], 1);
        if (pos) {
            cp++; cep += ce;
            int ti = bi[mi];
            float cx = pr4[mi].x, cy = pr4[mi].y, sw = pr4[mi].z, sh = pr4[mi].w;
            float4 t = t4[ti];
            float gx = ((t.x + t.z) * 0.5f - cx) / (0.1f * sw);
            float gy = ((t.y + t.w) * 0.5f - cy) / (0.1f * sh);
            float gw = logf((t.z - t.x) / sw) / 0.2f;
            float gh = logf((t.w - t.y) / sh) / 0.2f;
            const float* ld = &loc_data[(size_t)(b * P + p) * 4];
            ll += smooth_l1(ld[0] - gx) + smooth_l1(ld[1] - gy) +
                  smooth_l1(ld[2] - gw) + smooth_l1(ld[3] - gh);
            if (conf > 0) {
                cp1++;
                const float* lmd = &landm_data[(size_t)(b * P + p) * 10];
                for (int k5 = 0; k5 < 5; ++k5) {
                    float lx = (lm[ti][k5 * 2 + 0] - cx) / (0.1f * sw);
                    float ly = (lm[ti][k5 * 2 + 1] - cy) / (0.1f * sh);
                    llm += smooth_l1(lmd[k5 * 2 + 0] - lx) + smooth_l1(lmd[k5 * 2 + 1] - ly);
                }
            }
        }
    }
    float s_ll = wave_sum(ll), s_llm = wave_sum(llm), s_cep = wave_sum(cep);
    int s_cp = wave_sum_i(cp), s_cp1 = wave_sum_i(cp1);
    if (lid == 0) {
        wredf[0][wid] = s_ll; wredf[1][wid] = s_llm; wredf[2][wid] = s_cep;
        wredi[0][wid] = s_cp; wredi[1][wid] = s_cp1;
    }
    __syncthreads();
    if (tid == 0) {
        float ll_t = wredf[0][0] + wredf[0][1] + wredf[0][2] + wredf[0][3];
        float llm_t = wredf[1][0] + wredf[1][1] + wredf[1][2] + wredf[1][3];
        float cep_t = wredf[2][0] + wredf[2][1] + wredf[2][2] + wredf[2][3];
        int cp_t = wredi[0][0] + wredi[0][1] + wredi[0][2] + wredi[0][3];
        int cp1_t = wredi[1][0] + wredi[1][1] + wredi[1][2] + wredi[1][3];
        if (ll_t != 0.f)  atomicAdd(&gsum[0], ll_t);
        if (llm_t != 0.f) atomicAdd(&gsum[1], llm_t);
        if (cep_t != 0.f) atomicAdd(&pos_ce[b], cep_t);
        if (cp_t)  atomicAdd(&num_pos[b], cp_t);
        if (cp1_t) atomicAdd(np1_tot, cp1_t);
    }
    int* gh = hist + (size_t)b * HB;
#pragma unroll
    for (int i = tid; i < HB; i += 256) {
        int c = lhist[i];
        if (c) atomicAdd(&gh[i], c);
    }
}

// ---------------- kTail v2: whole rank row staged to LDS (160 KB/CU, 1 blk/CU);
// fixup applied in-LDS; all passes (sumgt + 3 radix refines + final sum) read LDS;
// bin selection via wave-parallel suffix scans. No candidate cap, no global rescans.
__global__ void __launch_bounds__(1024) kTail(
        const float* __restrict__ priors, const float* __restrict__ targets,
        const float* __restrict__ loc_data, const float* __restrict__ conf_data,
        const float* __restrict__ landm_data,
        const unsigned long long* __restrict__ bp_final,
        const float* __restrict__ rank, const int* __restrict__ hist,
        const int* __restrict__ num_pos, const float* __restrict__ pos_ce,
        float* __restrict__ gsum, int* __restrict__ np1_tot, int* __restrict__ np_tot,
        float* __restrict__ lossc_tot, int* __restrict__ done,
        float* __restrict__ out) {
    __shared__ __align__(16) unsigned lrow[P];   // 67.2 KB: the whole rank row
    __shared__ float4 t4[O];
    __shared__ float ta[O], lab[O];
    __shared__ int sp[O];
    __shared__ int lh[HB];
    __shared__ int chunkSum[256];
    __shared__ int suf[257];
    __shared__ int waveTot[4];
    __shared__ int hist2[256];
    __shared__ int s_np, s_bin0, s_kk0, s_bin, s_kk;
    __shared__ float wredf[16];
    __shared__ int wredi[16];
    __shared__ float s_sumgt;

    int b = blockIdx.x;
    int tid = threadIdx.x;
    const float* r = rank + (size_t)b * P;
    // ---- stage: whole row (vectorized), coarse hist, targets
    const float4* r4 = (const float4*)r;
    for (int i = tid; i < P / 4; i += 1024) {
        float4 q = r4[i];
        ((uint4*)lrow)[i] = make_uint4(__float_as_uint(q.x), __float_as_uint(q.y),
                                       __float_as_uint(q.z), __float_as_uint(q.w));
    }
    for (int i = tid; i < HB; i += 1024) lh[i] = hist[(size_t)b * HB + i];
    int p = 0, v = 0;
    if (tid < O) {
        const float* tt = &targets[(b * O + tid) * 15];
        float4 tj = make_float4(tt[0], tt[1], tt[2], tt[3]);
        t4[tid] = tj;
        ta[tid] = (tj.z - tj.x) * (tj.w - tj.y);
        lab[tid] = tt[14];
        unsigned long long kpk = bp_final[b * O + tid];
        p = (int)(0xFFFFFFFFu - (unsigned)(kpk & 0xFFFFFFFFu));
        float iou = __uint_as_float((unsigned)(kpk >> 32));
        v = (iou >= VALID_T) ? 1 : 0;
        sp[tid] = p;
    }
    __syncthreads();
    // ---- fixup (same float ops as before; rank fixed in LDS only)
    int dnp = 0, dn1 = 0;
    float dll = 0.f, dllm = 0.f, dce = 0.f;
    if (tid < O) {
        int j = tid;
        bool winner = true;                // last j with this p wins (numpy scatter)
        for (int jj = j + 1; jj < O; ++jj)
            if (sp[jj] == p) { winner = false; break; }
        if (winner) {
            float4 q = ((const float4*)priors)[p];
            float px1 = q.x - q.z * 0.5f, py1 = q.y - q.w * 0.5f;
            float px2 = q.x + q.z * 0.5f, py2 = q.y + q.w * 0.5f;
            float areab = (px2 - px1) * (py2 - py1);
            float bnum = 0.f, bden = 1.f; int bi = 0;
            for (int o = 0; o < O; ++o)     // ascending o: bit-identical to hot path
                iou_upd(t4[o], ta[o], px1, py1, px2, py2, areab, bnum, bden, bi, o);
            float best = bnum / bden;
            float ov_new = v ? 2.0f : best;
            int conf_old = (best >= THRESH) ? (int)lab[bi] : 0;
            int conf_new = (ov_new >= THRESH) ? (int)lab[j] : 0;
            float2 c01 = ((const float2*)conf_data)[b * P + p];
            float c0 = c01.x, c1 = c01.y;
            float lse = lse2(c0, c1);
            bool po = conf_old != 0, pn = conf_new != 0;
            float ceo = lse - (po ? c1 : c0), cen = lse - (pn ? c1 : c0);
            float rvo = po ? 0.f : ceo, rvn = pn ? 0.f : cen;
            if (__float_as_uint(rvo) != __float_as_uint(rvn)) {
                lrow[p] = __float_as_uint(rvn);   // LDS-only fix (winners have unique p)
                int bo = __float_as_uint(rvo) >> HSHIFT, bn = __float_as_uint(rvn) >> HSHIFT;
                if (bo != bn) { atomicAdd(&lh[bn], 1); atomicAdd(&lh[bo], -1); }
            }
            const float* ld = &loc_data[(size_t)(b * P + p) * 4];
            auto enc_ll = [&](int ti) -> float {    // same float ops as kD1 epilogue
                float4 t = t4[ti];
                float gx = ((t.x + t.z) * 0.5f - q.x) / (0.1f * q.z);
                float gy = ((t.y + t.w) * 0.5f - q.y) / (0.1f * q.w);
                float gw = logf((t.z - t.x) / q.z) / 0.2f;
                float gh = logf((t.w - t.y) / q.w) / 0.2f;
                return smooth_l1(ld[0] - gx) + smooth_l1(ld[1] - gy) +
                       smooth_l1(ld[2] - gw) + smooth_l1(ld[3] - gh);
            };
            if (po) dll -= enc_ll(bi);
            if (pn) dll += enc_ll(j);
            dce = (pn ? cen : 0.f) - (po ? ceo : 0.f);
            dnp = (int)pn - (int)po;
            const float* lmd = &landm_data[(size_t)(b * P + p) * 10];
            auto enc_lm = [&](int ti) -> float {
                const float* lmt = &targets[(b * O + ti) * 15 + 4];
                float sum = 0.f;
                for (int k5 = 0; k5 < 5; ++k5) {
                    float lx = (lmt[k5 * 2 + 0] - q.x) / (0.1f * q.z);
                    float ly = (lmt[k5 * 2 + 1] - q.y) / (0.1f * q.w);
                    sum += smooth_l1(lmd[k5 * 2 + 0] - lx) + smooth_l1(lmd[k5 * 2 + 1] - ly);
                }
                return sum;
            };
            if (conf_old > 0) dllm -= enc_lm(bi);
            if (conf_new > 0) dllm += enc_lm(j);
            dn1 = (int)(conf_new > 0) - (int)(conf_old > 0);
        }
    }
    float pce_reg = 0.f;
    if (tid < 64) {                        // wave 0 reduces the deltas
        float r_ll = wave_sum(dll), r_lm = wave_sum(dllm), r_ce = wave_sum(dce);
        int r_np = wave_sum_i(dnp), r_n1 = wave_sum_i(dn1);
        if (tid == 0) {
            if (r_ll != 0.f) atomicAdd(&gsum[0], r_ll);
            if (r_lm != 0.f) atomicAdd(&gsum[1], r_lm);
            pce_reg = pos_ce[b] + r_ce;    // row-private, kept in tid0's register
            int np = num_pos[b] + r_np;
            s_np = np;
            atomicAdd(np_tot, np);
            if (r_n1) atomicAdd(np1_tot, r_n1);
        }
    }
    __syncthreads();                       // lh atomics + lrow fixes + s_np visible
    // ---- findbin (parallel): chunk sums -> wave suffix scan -> unique winner
    int k = s_np * 7;
    if (k > P - 1) k = P - 1;
    if (tid < 256) {
        int cs = 0;
#pragma unroll
        for (int i = 0; i < HB / 256; ++i) cs += lh[tid * (HB / 256) + i];
        chunkSum[tid] = cs;
    }
    if (tid == 0) { s_bin0 = (k <= 0) ? -1 : 0; s_kk0 = (k <= 0) ? 0 : k; }
    __syncthreads();
    {
        int lane = tid & 63;
        int vv = (tid < 256) ? chunkSum[tid] : 0;
        vv = wave_sufscan(vv, lane);
        if (tid < 256 && lane == 0) waveTot[tid >> 6] = vv;
        __syncthreads();
        if (tid < 256) {
            int after = 0;
            for (int g = (tid >> 6) + 1; g < 4; ++g) after += waveTot[g];
            suf[tid] = vv + after;
            if (tid == 0) suf[256] = 0;
        }
        __syncthreads();
        if (k > 0 && tid < 256) {
            // winner chunk: first from top with running cum + chunk >= k
            if (suf[tid] >= k && suf[tid + 1] < k) {
                int cum = suf[tid + 1];
                for (int i = HB / 256 - 1; i >= 0; --i) {
                    int hv = lh[tid * (HB / 256) + i];
                    if (cum + hv >= k) { s_bin0 = tid * (HB / 256) + i; s_kk0 = k - cum; break; }
                    cum += hv;
                }
            }
        }
    }
    __syncthreads();
    int bin = s_bin0;
    int kk0 = s_kk0;
    float topk_b = 0.f;
    if (bin >= 0) {                        // block-uniform branch: barriers safe
        // ---- sumgt: same per-thread stride + reduction order as before (LDS reads)
        unsigned lo_bound = ((unsigned)(bin + 1)) << HSHIFT;
        float sumgt = 0.f;
        for (int pp = tid; pp < P; pp += 1024) {
            unsigned u = lrow[pp];
            if (u >= lo_bound) sumgt += __uint_as_float(u);
        }
        float sg = wave_sum(sumgt);
        if ((tid & 63) == 0) wredf[tid >> 6] = sg;
        __syncthreads();
        if (tid == 0) {
            float t = 0.f;
            for (int i = 0; i < 16; ++i) t += wredf[i];
            s_sumgt = t;
        }
        // ---- 3-pass radix refine, whole row from LDS (no candidate cap)
        unsigned pref = ((unsigned)bin) << HSHIFT;
        unsigned resolved = 0xFFFFFFFFu << HSHIFT;
        int kk = kk0;
        const int shifts[3] = {13, 5, 0};
        const int nbins[3] = {256, 256, 32};
        for (int pass = 0; pass < 3; ++pass) {
            int sh = shifts[pass], nb = nbins[pass];
            if (tid < nb) hist2[tid] = 0;
            __syncthreads();
            for (int i = tid; i < P / 4; i += 1024) {
                uint4 u4 = ((const uint4*)lrow)[i];
                if ((u4.x & resolved) == pref) atomicAdd(&hist2[(u4.x >> sh) & (nb - 1)], 1);
                if ((u4.y & resolved) == pref) atomicAdd(&hist2[(u4.y >> sh) & (nb - 1)], 1);
                if ((u4.z & resolved) == pref) atomicAdd(&hist2[(u4.z >> sh) & (nb - 1)], 1);
                if ((u4.w & resolved) == pref) atomicAdd(&hist2[(u4.w >> sh) & (nb - 1)], 1);
            }
            __syncthreads();
            // parallel bin select (suffix scan over nb bins)
            int lane = tid & 63;
            int vv = (tid < nb) ? hist2[tid] : 0;
            vv = wave_sufscan(vv, lane);
            if (tid < nb && lane == 0) waveTot[tid >> 6] = vv;
            __syncthreads();
            int ng = (nb + 63) >> 6;
            if (tid < nb) {
                int after = 0;
                for (int g = (tid >> 6) + 1; g < ng; ++g) after += waveTot[g];
                suf[tid] = vv + after;
                if (tid == 0) suf[nb] = 0;
            }
            __syncthreads();
            if (tid < nb) {
                if (suf[tid] >= kk && suf[tid + 1] < kk) { s_bin = tid; s_kk = kk - suf[tid + 1]; }
            }
            __syncthreads();
            pref |= ((unsigned)s_bin) << sh;
            resolved |= (unsigned)(nb - 1) << sh;
            kk = s_kk;
            __syncthreads();
        }
        float tv = __uint_as_float(pref);  // exact k-th largest value
        float sumS = 0.f; int cntS = 0;
        for (int pp = tid; pp < P; pp += 1024) {
            unsigned u = lrow[pp];
            if ((u >> HSHIFT) == (unsigned)bin) {
                float val = __uint_as_float(u);
                if (val > tv) { sumS += val; cntS++; }
            }
        }
        float s2 = wave_sum(sumS); int c2 = wave_sum_i(cntS);
        if ((tid & 63) == 0) { wredf[tid >> 6] = s2; wredi[tid >> 6] = c2; }
        __syncthreads();
        if (tid == 0) {
            float st = 0.f; int ct = 0;
            for (int i = 0; i < 16; ++i) { st += wredf[i]; ct += wredi[i]; }
            topk_b = s_sumgt + st + (float)(kk0 - ct) * tv;
        }
    }
    if (tid == 0) {
        atomicAdd(lossc_tot, pce_reg + topk_b);
        __threadfence();
        int old = atomicAdd(done, 1);
        if (old == B - 1) {                // last block finalizes (atomic reads: L2-fresh)
            float g0 = atomicAdd(&gsum[0], 0.f);
            float g1 = atomicAdd(&gsum[1], 0.f);
            float lc = atomicAdd(lossc_tot, 0.f);
            int np = atomicAdd(np_tot, 0);
            int n1 = atomicAdd(np1_tot, 0);
            float N = fmaxf((float)np, 1.f);
            float N1 = fmaxf((float)n1, 1.f);
            out[0] = g0 / N;
            out[1] = lc / N;
            out[2] = g1 / N1;
        }
    }
}

extern "C" void kernel_launch(void* const* d_in, const int* in_sizes, int n_in,
                              void* d_out, int out_size, void* d_ws, size_t ws_size,
                              hipStream_t stream) {
    const float* loc_data   = (const float*)d_in[0];
    const float* conf_data  = (const float*)d_in[1];
    const float* landm_data = (const float*)d_in[2];
    const float* priors     = (const float*)d_in[3];
    const float* targets    = (const float*)d_in[4];
    float* out = (float*)d_out;

    char* ws = (char*)d_ws;
    size_t off = 0;
    auto alloc = [&](size_t bytes) -> void* {
        void* pp = ws + off;
        off += (bytes + 255) & ~(size_t)255;
        return pp;
    };
    float* rank     = (float*)alloc((size_t)B * P * 4);
    unsigned long long* bp_final = (unsigned long long*)alloc((size_t)B * O * 8);
    // zero region: hist (B*HB ints) + accumulators, contiguous (one memset)
    size_t hist_bytes = (size_t)B * HB * 4;
    char* zbase = (char*)alloc(hist_bytes);
    int* hist = (int*)zbase;
    size_t acc_bytes = (size_t)(2 * B * 4 + 64);
    char* acc = (char*)alloc(acc_bytes);
    int*   num_pos      = (int*)acc;
    float* pos_ce       = (float*)(acc + B * 4);
    float* gsum         = (float*)(acc + 2 * B * 4);          // 2 floats
    int*   np1_tot      = (int*)(acc + 2 * B * 4 + 8);
    int*   np_tot       = (int*)(acc + 2 * B * 4 + 12);
    float* lossc_tot    = (float*)(acc + 2 * B * 4 + 16);
    int*   done         = (int*)(acc + 2 * B * 4 + 20);
    size_t zlen = (size_t)((acc + acc_bytes) - zbase);

    hipMemsetAsync(zbase, 0, zlen, stream);
    kMain<<<dim3(KD1B + KB2B), dim3(256), 0, stream>>>(loc_data, conf_data, landm_data,
                                                       priors, targets, rank, hist,
                                                       num_pos, pos_ce, gsum, np1_tot,
                                                       bp_final);
    kTail<<<dim3(B), dim3(1024), 0, stream>>>(priors, targets, loc_data, conf_data,
                                              landm_data, bp_final, rank, hist,
                                              num_pos, pos_ce, gsum, np1_tot, np_tot,
                                              lossc_tot, done, out);
}